// Round 1
// baseline (1002.979 us; speedup 1.0000x reference)
//
#include <hip/hip_runtime.h>
#include <math.h>

#define ALPHA 0.2f
#define MASKV -9000000000000000.0f

constexpr int N    = 9;
constexpr int H1n  = 3, D1 = 32;   // layer-1 heads, head dim
constexpr int HID  = 96;           // H1n*D1
constexpr int D2   = 16;           // layer-2 head dim
constexpr int OUTC = 48;           // 3*16
constexpr int P1   = 24;

// per-wave scratch layout (floats)
constexpr int O_OBS = 0;     // 9  (pad 12)
constexpr int O_S   = 12;    // 27 (pad 28)
constexpr int O_WH2 = 40;    // 432 [h][n][d]
constexpr int O_F1  = 472;   // 27 (pad 28)
constexpr int O_F2  = 500;   // 27 (pad 28)
constexpr int O_H2  = 528;   // 432 [n][c]
constexpr int O_SC  = 960;   // 9  (pad 12)
constexpr int O_U   = 972;   // union: h1[864]  OR  att[243]+pad | p[216]
constexpr int O_ATT = O_U;
constexpr int O_P   = O_U + 256;
constexpr int WSCR  = 1856;  // total per-wave scratch (16B aligned)

__global__ __launch_bounds__(256) void gnn_gat_kernel(
    const float* __restrict__ obs, const float* __restrict__ adj,
    const float* __restrict__ W1,  const float* __restrict__ a1,
    const float* __restrict__ W2,  const float* __restrict__ a2,
    const float* __restrict__ Wp1, const float* __restrict__ bp1,
    const float* __restrict__ Wp2, const float* __restrict__ bp2,
    float* __restrict__ out, int B)
{
    __shared__ float sW2[HID * OUTC];   // [i][c], c = h*16+d
    __shared__ float sWp1[OUTC * P1];   // [c][k]
    __shared__ float sW1[HID];          // [g*32+d1]
    __shared__ float sA2a[OUTC], sA2b[OUTC];
    __shared__ float sWp2[P1], sBp1[P1];
    __shared__ float sC12[2 * H1n];     // [2h]=c1, [2h+1]=c2
    __shared__ float sAdj[N * N];
    __shared__ float sBp2[1];
    __shared__ __align__(16) float scr4[4][WSCR];

    const int tid = threadIdx.x;

    // ---- cooperative weight staging (block-shared, batch-invariant) ----
    for (int t = tid; t < HID * OUTC; t += 256) {
        int i = t / OUTC, c = t - i * OUTC;
        int h = c >> 4, d = c & 15;
        sW2[t] = W2[(h * HID + i) * D2 + d];   // transpose to [i][c]
    }
    for (int t = tid; t < OUTC * P1; t += 256) sWp1[t] = Wp1[t];
    if (tid < HID) sW1[tid] = W1[tid];
    if (tid < OUTC) {
        int h = tid >> 4, d = tid & 15;
        sA2a[tid] = a2[h * 2 * D2 + d];
        sA2b[tid] = a2[h * 2 * D2 + D2 + d];
    }
    if (tid < P1) { sWp2[tid] = Wp2[tid]; sBp1[tid] = bp1[tid]; }
    if (tid < N * N) sAdj[tid] = adj[tid];
    if (tid == 0) sBp2[0] = bp2[0];
    if (tid < 2 * H1n) {
        int h = tid >> 1, which = tid & 1;
        float acc = 0.f;
        for (int d = 0; d < D1; ++d)
            acc += W1[h * D1 + d] * a1[h * 2 * D1 + which * D1 + d];
        sC12[tid] = acc;
    }
    __syncthreads();

    const int wave = tid >> 6, lane = tid & 63;
    float* scr = scr4[wave];

    const int gw = blockIdx.x * 4 + wave;
    const int nw = gridDim.x * 4;
    const int nIter = (B + nw - 1) / nw;

    for (int it = 0; it < nIter; ++it) {
        const int b = gw + it * nw;
        const bool active = (b < B);

        // A: load obs for this batch
        if (active && lane < N) scr[O_OBS + lane] = obs[(size_t)b * N + lane];
        __syncthreads();

        // B: layer-1 attention -> s[g][n] (27 lanes)
        if (active && lane < H1n * N) {
            int g = lane / N, n = lane - g * N;
            float c1 = sC12[2 * g], c2 = sC12[2 * g + 1];
            float f1 = c1 * scr[O_OBS + n];
            float e[N]; float m = -1e30f;
            #pragma unroll
            for (int j = 0; j < N; ++j) {
                float x = f1 + c2 * scr[O_OBS + j];
                x = (x > 0.f) ? x : ALPHA * x;
                x = (sAdj[n * N + j] > 0.f) ? x : MASKV;
                e[j] = x; m = fmaxf(m, x);
            }
            float sum = 0.f, sacc = 0.f;
            #pragma unroll
            for (int j = 0; j < N; ++j) {
                float p = __expf(e[j] - m);
                sum += p; sacc += p * scr[O_OBS + j];
            }
            scr[O_S + lane] = sacc / sum;
        }
        __syncthreads();

        // C: h1[n][i] = elu(s[g][n] * W1[i])   (all 64 lanes)
        if (active) {
            for (int t = lane; t < N * HID; t += 64) {
                int n = t / HID, i = t - n * HID;
                int g = i >> 5;
                float v = scr[O_S + g * N + n] * sW1[i];
                scr[O_U + t] = (v > 0.f) ? v : (__expf(v) - 1.f);
            }
        }
        __syncthreads();

        // D: Wh2[h][n][d] = sum_i h1[n][i]*W2[i][c]; f1/f2 via shfl (48 lanes)
        if (active && lane < OUTC) {
            const int c = lane, h = c >> 4, d = c & 15;
            float acc[N];
            #pragma unroll
            for (int n = 0; n < N; ++n) acc[n] = 0.f;
            for (int i = 0; i < HID; i += 4) {
                float w0 = sW2[(i + 0) * OUTC + c];
                float w1 = sW2[(i + 1) * OUTC + c];
                float w2v = sW2[(i + 2) * OUTC + c];
                float w3 = sW2[(i + 3) * OUTC + c];
                #pragma unroll
                for (int n = 0; n < N; ++n) {
                    const float4 hv = *(const float4*)&scr[O_U + n * HID + i];
                    acc[n] += hv.x * w0 + hv.y * w1 + hv.z * w2v + hv.w * w3;
                }
            }
            float va = sA2a[c], vb = sA2b[c];
            #pragma unroll
            for (int n = 0; n < N; ++n) {
                scr[O_WH2 + h * (N * D2) + n * D2 + d] = acc[n];
                float f1 = acc[n] * va, f2 = acc[n] * vb;
                #pragma unroll
                for (int mm = 8; mm >= 1; mm >>= 1) {
                    f1 += __shfl_xor(f1, mm, 16);
                    f2 += __shfl_xor(f2, mm, 16);
                }
                if (d == 0) { scr[O_F1 + h * N + n] = f1; scr[O_F2 + h * N + n] = f2; }
            }
        }
        __syncthreads();

        // E1: att[h][i][j] (27 lanes) — overlays h1 region (h1 dead now)
        if (active && lane < H1n * N) {
            int h = lane / N, i = lane - h * N;
            float f1i = scr[O_F1 + lane];
            float e[N]; float m = -1e30f;
            #pragma unroll
            for (int j = 0; j < N; ++j) {
                float x = f1i + scr[O_F2 + h * N + j];
                x = (x > 0.f) ? x : ALPHA * x;
                x = (sAdj[i * N + j] > 0.f) ? x : MASKV;
                e[j] = x; m = fmaxf(m, x);
            }
            float p[N]; float sum = 0.f;
            #pragma unroll
            for (int j = 0; j < N; ++j) { p[j] = __expf(e[j] - m); sum += p[j]; }
            float r = 1.f / sum;
            #pragma unroll
            for (int j = 0; j < N; ++j) scr[O_ATT + h * 81 + i * N + j] = p[j] * r;
        }
        __syncthreads();

        // E2: out2 -> h2[n][c] (48 lanes)
        if (active && lane < OUTC) {
            const int c = lane, h = c >> 4, d = c & 15;
            float o[N];
            #pragma unroll
            for (int i = 0; i < N; ++i) o[i] = 0.f;
            #pragma unroll
            for (int j = 0; j < N; ++j) {
                float wv = scr[O_WH2 + h * (N * D2) + j * D2 + d];
                #pragma unroll
                for (int i = 0; i < N; ++i)
                    o[i] += scr[O_ATT + h * 81 + i * N + j] * wv;
            }
            #pragma unroll
            for (int i = 0; i < N; ++i) scr[O_H2 + i * OUTC + c] = o[i];
        }
        __syncthreads();

        // F: p[n][k] = tanh(h2[n]·Wp1[:,k] + bp1[k])  (all lanes, 216 items)
        if (active) {
            for (int t = lane; t < N * P1; t += 64) {
                int n = t / P1, k = t - n * P1;
                float acc = sBp1[k];
                for (int cc = 0; cc < OUTC; ++cc)
                    acc += scr[O_H2 + n * OUTC + cc] * sWp1[cc * P1 + k];
                scr[O_P + t] = tanhf(acc);
            }
        }
        __syncthreads();

        // G: node scores (9 lanes)
        if (active && lane < N) {
            float acc = sBp2[0];
            #pragma unroll
            for (int k = 0; k < P1; ++k) acc += scr[O_P + lane * P1 + k] * sWp2[k];
            scr[O_SC + lane] = acc;
        }
        __syncthreads();

        // H: softmax over nodes + weighted sum -> out[b][c] (48 lanes)
        if (active && lane < OUTC) {
            float m = -1e30f;
            #pragma unroll
            for (int n = 0; n < N; ++n) m = fmaxf(m, scr[O_SC + n]);
            float sum = 0.f, acc = 0.f;
            #pragma unroll
            for (int n = 0; n < N; ++n) {
                float p = __expf(scr[O_SC + n] - m);
                sum += p; acc += p * scr[O_H2 + n * OUTC + lane];
            }
            out[(size_t)b * OUTC + lane] = acc / sum;
        }
        __syncthreads();
    }
}

extern "C" void kernel_launch(void* const* d_in, const int* in_sizes, int n_in,
                              void* d_out, int out_size, void* d_ws, size_t ws_size,
                              hipStream_t stream) {
    const float* obs = (const float*)d_in[0];
    const float* adj = (const float*)d_in[1];
    const float* W1  = (const float*)d_in[2];
    const float* a1  = (const float*)d_in[3];
    const float* W2  = (const float*)d_in[4];
    const float* a2  = (const float*)d_in[5];
    const float* Wp1 = (const float*)d_in[6];
    const float* bp1 = (const float*)d_in[7];
    const float* Wp2 = (const float*)d_in[8];
    const float* bp2 = (const float*)d_in[9];
    float* out = (float*)d_out;

    const int B = in_sizes[0] / N;

    // ~4 batches per wave: fine-grained grid for good tail behavior
    int blocks = (B + 15) / 16;
    if (blocks < 1) blocks = 1;
    if (blocks > 16384) blocks = 16384;

    gnn_gat_kernel<<<blocks, 256, 0, stream>>>(
        obs, adj, W1, a1, W2, a2, Wp1, bp1, Wp2, bp2, out, B);
}

// Round 2
// 621.398 us; speedup vs baseline: 1.6141x; 1.6141x over previous
//
#include <hip/hip_runtime.h>
#include <math.h>

#define ALPHA 0.2f
#define MASKV -9000000000000000.0f

constexpr int N    = 9;
constexpr int HID  = 96;
constexpr int D2   = 16;
constexpr int OUTC = 48;
constexpr int P1   = 24;

// per-group LDS scratch (floats)
constexpr int O_U  = 0;    // h1[9][48] (432) overlaid later by att[27][12] (324)
constexpr int O_S  = 432;  // s[27] + pad
constexpr int O_F1 = 460;  // f1[27] + pad
constexpr int O_F2 = 488;  // f2[3][12]
constexpr int GSCR = 524;  // per-group stride (16B-aligned; q*131 mod 32 -> <=2-way bank overlap = free)

#define WAVE_SYNC() asm volatile("s_waitcnt lgkmcnt(0)" ::: "memory")

__device__ __forceinline__ float fast_rcp(float x) { return __builtin_amdgcn_rcpf(x); }
__device__ __forceinline__ float tanh_fast(float x) {
    float e = __expf(x + x);               // e^(2x)
    return 1.f - 2.f * fast_rcp(e + 1.f);  // inf-safe: e=inf -> 1; e=0 -> -1
}
__device__ __forceinline__ float elu_f(float v) {
    return v > 0.f ? v : (__expf(v) - 1.f);
}

// pre-pass: w2t[c][i] = W2[h][i][d],  c = h*16+d   (4608 floats into d_ws)
__global__ void prep_kernel(const float* __restrict__ W2, float* __restrict__ w2t) {
    int t = blockIdx.x * 256 + threadIdx.x;
    if (t < OUTC * HID) {
        int c = t / HID, i = t - c * HID;
        int h = c >> 4, d = c & 15;
        w2t[t] = W2[(h * HID + i) * D2 + d];
    }
}

__global__ __launch_bounds__(128, 2) void gnn_gat_kernel(
    const float* __restrict__ obs, const float* __restrict__ adj,
    const float* __restrict__ W1,  const float* __restrict__ a1,
    const float* __restrict__ a2,
    const float* __restrict__ Wp1, const float* __restrict__ bp1,
    const float* __restrict__ Wp2, const float* __restrict__ bp2,
    const float* __restrict__ w2t,
    float* __restrict__ out, int B)
{
    __shared__ float sW1[96];
    __shared__ __align__(16) float smem[2][8][GSCR];

    const int tid  = threadIdx.x;
    const int wv   = tid >> 6;
    const int lane = tid & 63;
    const int q    = lane >> 3;   // group (sub-batch) within wave
    const int l8   = lane & 7;    // lane within group
    float* scr = smem[wv][q];

    // ---- staging (per-wave duplicated writes of identical values: benign) ----
    for (int t = lane; t < 96; t += 64) sW1[t] = W1[t];

    // layer-1 collapsed coefficients c1[g], c2[g]
    float c12[6];
    #pragma unroll
    for (int g = 0; g < 3; ++g) {
        float s1 = 0.f, s2 = 0.f;
        for (int d = 0; d < 32; ++d) {
            float w = W1[g * 32 + d];
            s1 += w * a1[g * 64 + d];
            s2 += w * a1[g * 64 + 32 + d];
        }
        c12[2 * g] = s1; c12[2 * g + 1] = s2;
    }
    // a2 slices for the d-distributed butterfly (lane owns d = l8 and d = l8+8 per head)
    float a2a0[3], a2a1[3], a2b0[3], a2b1[3];
    #pragma unroll
    for (int h = 0; h < 3; ++h) {
        a2a0[h] = a2[h * 32 + l8];
        a2a1[h] = a2[h * 32 + 8 + l8];
        a2b0[h] = a2[h * 32 + 16 + l8];
        a2b1[h] = a2[h * 32 + 24 + l8];
    }
    // adjacency bitmasks: rows 3r..3r+2 in am[r], bit 9*(row%3)+col
    unsigned am[3];
    #pragma unroll
    for (int r = 0; r < 3; ++r) {
        unsigned u = 0;
        for (int t = 0; t < 27; ++t)
            u |= (adj[r * 27 + t] > 0.f ? 1u : 0u) << t;
        am[r] = u;
    }
    const float bp2r = bp2[0];

    const int gid0    = (blockIdx.x * 2 + wv) * 8 + q;
    const int gstride = gridDim.x * 16;

    for (int b = gid0; b < B; b += gstride) {
        // ---- A: obs -> regs (9 scalar loads, L2-resident stream) ----
        float o_r[9];
        #pragma unroll
        for (int j = 0; j < 9; ++j) o_r[j] = obs[(size_t)b * 9 + j];

        // ---- B: layer-1 attention -> s[g][n] (27 items over 8 lanes) ----
        for (int t = l8; t < 27; t += 8) {
            int g = (t >= 18) ? 2 : (t >= 9 ? 1 : 0);
            int n = t - 9 * g;
            float c1 = c12[2 * g], c2 = c12[2 * g + 1];
            float f1 = c1 * o_r[n];
            unsigned rbits = (am[n / 3] >> (9 * (n % 3))) & 0x1FFu;
            float e[9], m = -3.0e38f;
            #pragma unroll
            for (int j = 0; j < 9; ++j) {
                float x = f1 + c2 * o_r[j];
                x = x > 0.f ? x : ALPHA * x;
                x = ((rbits >> j) & 1) ? x : MASKV;
                e[j] = x; m = fmaxf(m, x);
            }
            float sum = 0.f, sw = 0.f;
            #pragma unroll
            for (int j = 0; j < 9; ++j) {
                float p = __expf(e[j] - m);
                sum += p; sw += p * o_r[j];
            }
            scr[O_S + t] = sw * fast_rcp(sum);
        }
        WAVE_SYNC();

        // ---- C/D: h1 (two K-halves) + GEMM Wh2 = h1 @ W2T,  acc[n][k] <-> c = l8+8k ----
        float acc[9][6];
        #pragma unroll
        for (int n = 0; n < 9; ++n)
            #pragma unroll
            for (int k = 0; k < 6; ++k) acc[n][k] = 0.f;

        for (int p = 0; p < 2; ++p) {
            // C: fill h1[n][i_loc] for i = 48p .. 48p+47
            for (int t = l8; t < 108; t += 8) {
                int n = t / 12, ib = t - 12 * n;
                int i = 48 * p + 4 * ib;
                float sv = scr[O_S + (i >> 5) * 9 + n];
                const float4 w4 = *(const float4*)&sW1[i];
                float4 hv;
                hv.x = elu_f(sv * w4.x);
                hv.y = elu_f(sv * w4.y);
                hv.z = elu_f(sv * w4.z);
                hv.w = elu_f(sv * w4.w);
                *(float4*)&scr[O_U + n * 48 + 4 * ib] = hv;
            }
            WAVE_SYNC();

            // D: accumulate this K-half; weights streamed from global (L1-resident, prefetch depth 1)
            const float* wt = w2t + 48 * p;
            float4 wc[6];
            #pragma unroll
            for (int k = 0; k < 6; ++k)
                wc[k] = *(const float4*)&wt[(l8 + 8 * k) * 96];
            for (int ib = 0; ib < 12; ++ib) {
                float4 wn[6];
                if (ib < 11) {
                    #pragma unroll
                    for (int k = 0; k < 6; ++k)
                        wn[k] = *(const float4*)&wt[(l8 + 8 * k) * 96 + 4 * (ib + 1)];
                }
                #pragma unroll
                for (int n = 0; n < 9; ++n) {
                    const float4 hv = *(const float4*)&scr[O_U + n * 48 + 4 * ib];
                    #pragma unroll
                    for (int k = 0; k < 6; ++k)
                        acc[n][k] += hv.x * wc[k].x + hv.y * wc[k].y
                                   + hv.z * wc[k].z + hv.w * wc[k].w;
                }
                #pragma unroll
                for (int k = 0; k < 6; ++k) wc[k] = wn[k];
            }
            WAVE_SYNC();
        }

        // ---- f1/f2 for layer-2 attention: butterfly over the 8 d-lanes, write to LDS ----
        #pragma unroll
        for (int h = 0; h < 3; ++h) {
            #pragma unroll
            for (int n = 0; n < 9; ++n) {
                float v1 = acc[n][2 * h] * a2a0[h] + acc[n][2 * h + 1] * a2a1[h];
                float v2 = acc[n][2 * h] * a2b0[h] + acc[n][2 * h + 1] * a2b1[h];
                #pragma unroll
                for (int mm = 1; mm <= 4; mm <<= 1) {
                    v1 += __shfl_xor(v1, mm, 8);
                    v2 += __shfl_xor(v2, mm, 8);
                }
                if (((h * 9 + n) & 7) == l8) {
                    scr[O_F1 + h * 9 + n]  = v1;
                    scr[O_F2 + h * 12 + n] = v2;
                }
            }
        }
        WAVE_SYNC();

        // ---- E1: att rows (27 over 8 lanes) -> LDS att[t][12] overlaying h1 ----
        for (int t = l8; t < 27; t += 8) {
            int h = (t >= 18) ? 2 : (t >= 9 ? 1 : 0);
            int i = t - 9 * h;
            float f1i = scr[O_F1 + t];
            float f2r[9];
            #pragma unroll
            for (int j = 0; j < 9; ++j) f2r[j] = scr[O_F2 + h * 12 + j];
            unsigned rbits = (am[i / 3] >> (9 * (i % 3))) & 0x1FFu;
            float e[9], m = -3.0e38f;
            #pragma unroll
            for (int j = 0; j < 9; ++j) {
                float x = f1i + f2r[j];
                x = x > 0.f ? x : ALPHA * x;
                x = ((rbits >> j) & 1) ? x : MASKV;
                e[j] = x; m = fmaxf(m, x);
            }
            float p[9], sum = 0.f;
            #pragma unroll
            for (int j = 0; j < 9; ++j) { p[j] = __expf(e[j] - m); sum += p[j]; }
            float r = fast_rcp(sum);
            float4 p03 = { p[0] * r, p[1] * r, p[2] * r, p[3] * r };
            float4 p47 = { p[4] * r, p[5] * r, p[6] * r, p[7] * r };
            *(float4*)&scr[O_U + t * 12]     = p03;
            *(float4*)&scr[O_U + t * 12 + 4] = p47;
            scr[O_U + t * 12 + 8] = p[8] * r;
        }
        WAVE_SYNC();

        // ---- E2: h2 = att @ Wh2, in-place into acc (per head, two columns at a time) ----
        #pragma unroll
        for (int h = 0; h < 3; ++h) {
            float t0[9], t1[9];
            #pragma unroll
            for (int i = 0; i < 9; ++i) {
                const float4 r03 = *(const float4*)&scr[O_U + (h * 9 + i) * 12];
                const float4 r47 = *(const float4*)&scr[O_U + (h * 9 + i) * 12 + 4];
                const float  r8  = scr[O_U + (h * 9 + i) * 12 + 8];
                t0[i] = r03.x * acc[0][2*h] + r03.y * acc[1][2*h] + r03.z * acc[2][2*h]
                      + r03.w * acc[3][2*h] + r47.x * acc[4][2*h] + r47.y * acc[5][2*h]
                      + r47.z * acc[6][2*h] + r47.w * acc[7][2*h] + r8 * acc[8][2*h];
                t1[i] = r03.x * acc[0][2*h+1] + r03.y * acc[1][2*h+1] + r03.z * acc[2][2*h+1]
                      + r03.w * acc[3][2*h+1] + r47.x * acc[4][2*h+1] + r47.y * acc[5][2*h+1]
                      + r47.z * acc[6][2*h+1] + r47.w * acc[7][2*h+1] + r8 * acc[8][2*h+1];
            }
            #pragma unroll
            for (int i = 0; i < 9; ++i) { acc[i][2*h] = t0[i]; acc[i][2*h+1] = t1[i]; }
        }

        // ---- F+G: scores = tanh(h2 @ Wp1 + bp1) @ Wp2 + bp2 (butterfly over 8 c-lanes) ----
        float score[9];
        #pragma unroll
        for (int n = 0; n < 9; ++n) score[n] = bp2r;

        float4 wp[6], bq, wq;
        #pragma unroll
        for (int k = 0; k < 6; ++k)
            wp[k] = *(const float4*)&Wp1[(l8 + 8 * k) * 24];
        bq = *(const float4*)&bp1[0];
        wq = *(const float4*)&Wp2[0];
        for (int kb = 0; kb < 6; ++kb) {
            float4 wpn[6], bqn, wqn;
            if (kb < 5) {
                #pragma unroll
                for (int k = 0; k < 6; ++k)
                    wpn[k] = *(const float4*)&Wp1[(l8 + 8 * k) * 24 + 4 * (kb + 1)];
                bqn = *(const float4*)&bp1[4 * (kb + 1)];
                wqn = *(const float4*)&Wp2[4 * (kb + 1)];
            }
            #pragma unroll
            for (int n = 0; n < 9; ++n) {
                float4 part;
                part.x = acc[n][0]*wp[0].x + acc[n][1]*wp[1].x + acc[n][2]*wp[2].x
                       + acc[n][3]*wp[3].x + acc[n][4]*wp[4].x + acc[n][5]*wp[5].x;
                part.y = acc[n][0]*wp[0].y + acc[n][1]*wp[1].y + acc[n][2]*wp[2].y
                       + acc[n][3]*wp[3].y + acc[n][4]*wp[4].y + acc[n][5]*wp[5].y;
                part.z = acc[n][0]*wp[0].z + acc[n][1]*wp[1].z + acc[n][2]*wp[2].z
                       + acc[n][3]*wp[3].z + acc[n][4]*wp[4].z + acc[n][5]*wp[5].z;
                part.w = acc[n][0]*wp[0].w + acc[n][1]*wp[1].w + acc[n][2]*wp[2].w
                       + acc[n][3]*wp[3].w + acc[n][4]*wp[4].w + acc[n][5]*wp[5].w;
                #pragma unroll
                for (int mm = 1; mm <= 4; mm <<= 1) {
                    part.x += __shfl_xor(part.x, mm, 8);
                    part.y += __shfl_xor(part.y, mm, 8);
                    part.z += __shfl_xor(part.z, mm, 8);
                    part.w += __shfl_xor(part.w, mm, 8);
                }
                float tx = tanh_fast(part.x + bq.x);
                float ty = tanh_fast(part.y + bq.y);
                float tz = tanh_fast(part.z + bq.z);
                float tw = tanh_fast(part.w + bq.w);
                score[n] += tx * wq.x + ty * wq.y + tz * wq.z + tw * wq.w;
            }
            #pragma unroll
            for (int k = 0; k < 6; ++k) wp[k] = wpn[k];
            bq = bqn; wq = wqn;
        }

        // ---- H: node softmax + weighted sum -> out[b][48] ----
        float mx = score[0];
        #pragma unroll
        for (int n = 1; n < 9; ++n) mx = fmaxf(mx, score[n]);
        float wn9[9], sum = 0.f;
        #pragma unroll
        for (int n = 0; n < 9; ++n) { wn9[n] = __expf(score[n] - mx); sum += wn9[n]; }
        float r = fast_rcp(sum);
        #pragma unroll
        for (int n = 0; n < 9; ++n) wn9[n] *= r;
        #pragma unroll
        for (int k = 0; k < 6; ++k) {
            float ov = 0.f;
            #pragma unroll
            for (int n = 0; n < 9; ++n) ov += wn9[n] * acc[n][k];
            out[(size_t)b * 48 + l8 + 8 * k] = ov;
        }
        WAVE_SYNC();
    }
}

extern "C" void kernel_launch(void* const* d_in, const int* in_sizes, int n_in,
                              void* d_out, int out_size, void* d_ws, size_t ws_size,
                              hipStream_t stream) {
    const float* obs = (const float*)d_in[0];
    const float* adj = (const float*)d_in[1];
    const float* W1  = (const float*)d_in[2];
    const float* a1  = (const float*)d_in[3];
    const float* W2  = (const float*)d_in[4];
    const float* a2  = (const float*)d_in[5];
    const float* Wp1 = (const float*)d_in[6];
    const float* bp1 = (const float*)d_in[7];
    const float* Wp2 = (const float*)d_in[8];
    const float* bp2 = (const float*)d_in[9];
    float* out = (float*)d_out;
    float* w2t = (float*)d_ws;

    const int B = in_sizes[0] / N;

    prep_kernel<<<(OUTC * HID + 255) / 256, 256, 0, stream>>>(W2, w2t);

    // 2048 blocks x 2 waves x 8 groups = 32768 group-slots -> 4 batches per group at B=131072
    int blocks = 2048;
    gnn_gat_kernel<<<blocks, 128, 0, stream>>>(
        obs, adj, W1, a1, a2, Wp1, bp1, Wp2, bp2, w2t, out, B);
}

// Round 3
// 362.186 us; speedup vs baseline: 2.7692x; 1.7157x over previous
//
#include <hip/hip_runtime.h>
#include <math.h>

typedef _Float16 h16;
typedef _Float16 v2h __attribute__((ext_vector_type(2)));

#define ALPHA 0.2f
#define MASKV -9000000000000000.0f

constexpr int GSCR = 268;   // floats per group scratch slot (268 mod 32 = 12 -> b128 reads of the 8 groups tile all 32 banks)
constexpr int O_S  = 0;     // s[27] f32
constexpr int O_F1 = 28;    // f1[27] f32
constexpr int O_F2 = 56;    // f2[3][10] f32
constexpr int O_U  = 92;    // byte 368 (16B aligned): h1 tile [9][32] f16 (576B) / att [27][12] f16 (648B)
// h2 overlay lives at group base (floats 0..215): used only after s/f1/f2/att are dead.

#if defined(__has_builtin)
#  if __has_builtin(__builtin_amdgcn_fdot2)
#    define FDOT2(a,b,c) __builtin_amdgcn_fdot2((a),(b),(c),false)
#  endif
#endif
#ifndef FDOT2
__device__ __forceinline__ float fdot2_sw(v2h a, v2h b, float c) {
    return c + (float)a.x*(float)b.x + (float)a.y*(float)b.y;
}
#  define FDOT2(a,b,c) fdot2_sw((a),(b),(c))
#endif

union U4 { float4 f; v2h h[4]; };
union U2 { float2 f; v2h h[2]; };
union U1 { float  f; v2h h;    };

#define WAVE_SYNC() asm volatile("s_waitcnt lgkmcnt(0)" ::: "memory")

__device__ __forceinline__ float fast_rcp(float x) { return __builtin_amdgcn_rcpf(x); }
__device__ __forceinline__ float tanh_fast(float x) {
    float e = __expf(x + x);
    return 1.f - 2.f * fast_rcp(e + 1.f);
}

// ws layout (halves): [0,4608): w2H[c][i] (48x96)  [4608,5760): wp1P pair-slots:
//   wp1P[k][s] = { Wp1[c_lo][k], Wp1[c_hi][k] },  s=3*l8+kp, c_lo=l8+16*kp, c_hi=c_lo+8
__global__ void prep_kernel(const float* __restrict__ W2, const float* __restrict__ Wp1,
                            h16* __restrict__ ws) {
    int t = blockIdx.x * 256 + threadIdx.x;
    if (t < 48 * 96) {
        int c = t / 96, i = t - c * 96;
        int h = c >> 4, d = c & 15;
        ws[t] = (h16)W2[(h * 96 + i) * 16 + d];
    } else if (t < 48 * 96 + 576) {
        int t2 = t - 48 * 96;
        int k = t2 / 24, s = t2 - k * 24;
        int l = s / 3, kp = s - 3 * l;
        int clo = l + 16 * kp, chi = clo + 8;
        ws[4608 + 2 * t2]     = (h16)Wp1[clo * 24 + k];
        ws[4608 + 2 * t2 + 1] = (h16)Wp1[chi * 24 + k];
    }
}

__global__ __launch_bounds__(128, 4) void gnn_gat_kernel(
    const float* __restrict__ obs, const float* __restrict__ adj,
    const float* __restrict__ W1,  const float* __restrict__ a1,
    const float* __restrict__ a2,  const float* __restrict__ bp1,
    const float* __restrict__ Wp2, const h16* __restrict__ ws,
    float* __restrict__ out, int B)
{
    __shared__ float sW1[96];
    __shared__ float sAdj[81];
    __shared__ float sC12[6];
    __shared__ __align__(16) float smem[16 * GSCR];

    const int tid = threadIdx.x;
    if (tid < 96) sW1[tid] = W1[tid];
    if (tid < 81) sAdj[tid] = adj[tid];
    if (tid < 6) {
        int gg = tid >> 1, w = tid & 1;
        float s = 0.f;
        for (int d = 0; d < 32; ++d)
            s += W1[gg * 32 + d] * a1[gg * 64 + w * 32 + d];
        sC12[tid] = s;
    }
    __syncthreads();

    const int wv = tid >> 6, lane = tid & 63;
    const int q = lane >> 3, l8 = lane & 7;
    float* g = smem + (wv * 8 + q) * GSCR;
    float4* hUf4 = (float4*)(g + O_U);            // h1 tile rows: 4 float4 each
    float4* h2f4 = (float4*)g;                    // h2 rows: 6 float4 each
    const float4* wsf4 = (const float4*)ws;

    float c12[6];
    #pragma unroll
    for (int i = 0; i < 6; ++i) c12[i] = sC12[i];
    float a2a0[3], a2a1[3], a2b0[3], a2b1[3];
    #pragma unroll
    for (int h = 0; h < 3; ++h) {
        a2a0[h] = a2[h * 32 + l8];
        a2a1[h] = a2[h * 32 + 8 + l8];
        a2b0[h] = a2[h * 32 + 16 + l8];
        a2b1[h] = a2[h * 32 + 24 + l8];
    }
    unsigned am[3];
    #pragma unroll
    for (int r = 0; r < 3; ++r) {
        unsigned u = 0;
        for (int t = 0; t < 27; ++t)
            u |= (sAdj[r * 27 + t] > 0.f ? 1u : 0u) << t;
        am[r] = u;
    }
    float wq[3], bq[3];
    #pragma unroll
    for (int kk = 0; kk < 3; ++kk) {
        wq[kk] = Wp2[l8 + 8 * kk];
        bq[kk] = bp1[l8 + 8 * kk];
    }

    const int slots = gridDim.x * 16;
    for (int b = (blockIdx.x * 2 + wv) * 8 + q; b < B; b += slots) {
        // ---- A: obs (group-broadcast loads) ----
        float o_r[9];
        #pragma unroll
        for (int j = 0; j < 9; ++j) o_r[j] = obs[(size_t)b * 9 + j];

        // ---- B: layer-1 collapsed attention -> s[g][n] in LDS ----
        for (int t = l8; t < 27; t += 8) {
            int gg = (t >= 18) ? 2 : (t >= 9 ? 1 : 0);
            int n = t - 9 * gg;
            float f1 = c12[2 * gg] * o_r[n];
            float c2 = c12[2 * gg + 1];
            unsigned rbits = (am[n / 3] >> (9 * (n % 3))) & 0x1FFu;
            float e[9], m = -3.0e38f;
            #pragma unroll
            for (int j = 0; j < 9; ++j) {
                float x = f1 + c2 * o_r[j];
                x = x > 0.f ? x : ALPHA * x;
                x = ((rbits >> j) & 1) ? x : MASKV;
                e[j] = x; m = fmaxf(m, x);
            }
            float sum = 0.f, sw = 0.f;
            #pragma unroll
            for (int j = 0; j < 9; ++j) {
                float p = __expf(e[j] - m);
                sum += p; sw += p * o_r[j];
            }
            g[O_S + t] = sw * fast_rcp(sum);
        }
        WAVE_SYNC();

        // ---- C/D: 3 K-tiles of 32; h1 f16 in LDS, GEMM via v_dot2 ----
        float acc[9][6];
        #pragma unroll
        for (int n = 0; n < 9; ++n)
            #pragma unroll
            for (int k = 0; k < 6; ++k) acc[n][k] = 0.f;

        for (int p = 0; p < 3; ++p) {
            // C: h1[n][0..31] = elu(s[p][n] * W1[32p..32p+31]) as f16
            #pragma unroll
            for (int it = 0; it < 5; ++it) {
                int t = l8 + 8 * it;
                if (t < 36) {
                    int n = t >> 2, ib = t & 3;
                    int i0 = 32 * p + 8 * ib;
                    float sv = g[O_S + p * 9 + n];
                    float4 wa = *(const float4*)&sW1[i0];
                    float4 wb = *(const float4*)&sW1[i0 + 4];
                    float v0 = sv * wa.x, v1 = sv * wa.y, v2 = sv * wa.z, v3 = sv * wa.w;
                    float v4 = sv * wb.x, v5 = sv * wb.y, v6 = sv * wb.z, v7 = sv * wb.w;
                    v0 = v0 > 0.f ? v0 : __expf(v0) - 1.f;
                    v1 = v1 > 0.f ? v1 : __expf(v1) - 1.f;
                    v2 = v2 > 0.f ? v2 : __expf(v2) - 1.f;
                    v3 = v3 > 0.f ? v3 : __expf(v3) - 1.f;
                    v4 = v4 > 0.f ? v4 : __expf(v4) - 1.f;
                    v5 = v5 > 0.f ? v5 : __expf(v5) - 1.f;
                    v6 = v6 > 0.f ? v6 : __expf(v6) - 1.f;
                    v7 = v7 > 0.f ? v7 : __expf(v7) - 1.f;
                    U4 u;
                    u.h[0] = (v2h){(h16)v0, (h16)v1};
                    u.h[1] = (v2h){(h16)v2, (h16)v3};
                    u.h[2] = (v2h){(h16)v4, (h16)v5};
                    u.h[3] = (v2h){(h16)v6, (h16)v7};
                    hUf4[n * 4 + ib] = u.f;
                }
            }
            WAVE_SYNC();

            // D: acc[n][k] += h1[n][i:i+8] . w2[c][i:i+8]
            #pragma unroll
            for (int ib = 0; ib < 4; ++ib) {
                U4 w[6];
                #pragma unroll
                for (int k = 0; k < 6; ++k)
                    w[k].f = wsf4[(l8 + 8 * k) * 12 + p * 4 + ib];
                #pragma unroll
                for (int n = 0; n < 9; ++n) {
                    U4 hh; hh.f = hUf4[n * 4 + ib];
                    #pragma unroll
                    for (int k = 0; k < 6; ++k) {
                        float a = acc[n][k];
                        a = FDOT2(hh.h[0], w[k].h[0], a);
                        a = FDOT2(hh.h[1], w[k].h[1], a);
                        a = FDOT2(hh.h[2], w[k].h[2], a);
                        a = FDOT2(hh.h[3], w[k].h[3], a);
                        acc[n][k] = a;
                    }
                }
            }
            WAVE_SYNC();
        }

        // ---- f1/f2 for layer-2 attention (butterfly over 8 d-lanes) ----
        #pragma unroll
        for (int h = 0; h < 3; ++h) {
            #pragma unroll
            for (int n = 0; n < 9; ++n) {
                float v1 = acc[n][2 * h] * a2a0[h] + acc[n][2 * h + 1] * a2a1[h];
                float v2 = acc[n][2 * h] * a2b0[h] + acc[n][2 * h + 1] * a2b1[h];
                v1 += __shfl_xor(v1, 1, 8); v1 += __shfl_xor(v1, 2, 8); v1 += __shfl_xor(v1, 4, 8);
                v2 += __shfl_xor(v2, 1, 8); v2 += __shfl_xor(v2, 2, 8); v2 += __shfl_xor(v2, 4, 8);
                if (((h * 9 + n) & 7) == l8) {
                    g[O_F1 + h * 9 + n]  = v1;
                    g[O_F2 + h * 10 + n] = v2;
                }
            }
        }
        WAVE_SYNC();

        // ---- E1: att rows -> f16 LDS [27][12] ----
        for (int t = l8; t < 27; t += 8) {
            int h = (t >= 18) ? 2 : (t >= 9 ? 1 : 0);
            int i = t - 9 * h;
            float f1i = g[O_F1 + t];
            float f2r[9];
            #pragma unroll
            for (int j = 0; j < 9; ++j) f2r[j] = g[O_F2 + h * 10 + j];
            unsigned rbits = (am[i / 3] >> (9 * (i % 3))) & 0x1FFu;
            float e[9], m = -3.0e38f;
            #pragma unroll
            for (int j = 0; j < 9; ++j) {
                float x = f1i + f2r[j];
                x = x > 0.f ? x : ALPHA * x;
                x = ((rbits >> j) & 1) ? x : MASKV;
                e[j] = x; m = fmaxf(m, x);
            }
            float p[9], sum = 0.f;
            #pragma unroll
            for (int j = 0; j < 9; ++j) { p[j] = __expf(e[j] - m); sum += p[j]; }
            float r = fast_rcp(sum);
            char* row = (char*)(g + O_U) + t * 24;
            U2 u01, u23; U1 u4;
            u01.h[0] = (v2h){(h16)(p[0] * r), (h16)(p[1] * r)};
            u01.h[1] = (v2h){(h16)(p[2] * r), (h16)(p[3] * r)};
            u23.h[0] = (v2h){(h16)(p[4] * r), (h16)(p[5] * r)};
            u23.h[1] = (v2h){(h16)(p[6] * r), (h16)(p[7] * r)};
            u4.h     = (v2h){(h16)(p[8] * r), (h16)0.f};
            *(float2*)(row)      = u01.f;
            *(float2*)(row + 8)  = u23.f;
            *(float*)(row + 16)  = u4.f;
        }
        WAVE_SYNC();

        // ---- E2: h2 = att @ Wh2, in place into acc ----
        #pragma unroll
        for (int h = 0; h < 3; ++h) {
            float t0[9], t1[9];
            #pragma unroll
            for (int i = 0; i < 9; ++i) {
                const char* row = (const char*)(g + O_U) + (h * 9 + i) * 24;
                U2 a01, a23; U1 a4;
                a01.f = *(const float2*)row;
                a23.f = *(const float2*)(row + 8);
                a4.f  = *(const float*)(row + 16);
                float pj[9];
                pj[0] = (float)a01.h[0].x; pj[1] = (float)a01.h[0].y;
                pj[2] = (float)a01.h[1].x; pj[3] = (float)a01.h[1].y;
                pj[4] = (float)a23.h[0].x; pj[5] = (float)a23.h[0].y;
                pj[6] = (float)a23.h[1].x; pj[7] = (float)a23.h[1].y;
                pj[8] = (float)a4.h.x;
                float s0 = 0.f, s1 = 0.f;
                #pragma unroll
                for (int j = 0; j < 9; ++j) {
                    s0 += pj[j] * acc[j][2 * h];
                    s1 += pj[j] * acc[j][2 * h + 1];
                }
                t0[i] = s0; t1[i] = s1;
            }
            #pragma unroll
            for (int i = 0; i < 9; ++i) { acc[i][2 * h] = t0[i]; acc[i][2 * h + 1] = t1[i]; }
        }

        // ---- F0: pack h2 to f16 pair-slots in LDS (overlay at group base) ----
        #pragma unroll
        for (int n = 0; n < 9; ++n) {
            #pragma unroll
            for (int kp = 0; kp < 3; ++kp) {
                U1 u; u.h = (v2h){(h16)acc[n][2 * kp], (h16)acc[n][2 * kp + 1]};
                ((float*)g)[n * 24 + 3 * l8 + kp] = u.f;
            }
        }
        WAVE_SYNC();

        // ---- F+G: scores via dot2 against pre-packed Wp1; butterfly once per n ----
        float sp[9];
        #pragma unroll
        for (int n = 0; n < 9; ++n) sp[n] = 0.f;
        #pragma unroll
        for (int kk = 0; kk < 3; ++kk) {
            int k = l8 + 8 * kk;
            U4 w0, w1, w2u, w3, w4, w5;
            w0.f = wsf4[576 + k * 6 + 0];
            w1.f = wsf4[576 + k * 6 + 1];
            w2u.f = wsf4[576 + k * 6 + 2];
            w3.f = wsf4[576 + k * 6 + 3];
            w4.f = wsf4[576 + k * 6 + 4];
            w5.f = wsf4[576 + k * 6 + 5];
            #pragma unroll
            for (int n = 0; n < 9; ++n) {
                float a = 0.f;
                U4 x;
                x.f = h2f4[n * 6 + 0];
                a = FDOT2(x.h[0], w0.h[0], a); a = FDOT2(x.h[1], w0.h[1], a);
                a = FDOT2(x.h[2], w0.h[2], a); a = FDOT2(x.h[3], w0.h[3], a);
                x.f = h2f4[n * 6 + 1];
                a = FDOT2(x.h[0], w1.h[0], a); a = FDOT2(x.h[1], w1.h[1], a);
                a = FDOT2(x.h[2], w1.h[2], a); a = FDOT2(x.h[3], w1.h[3], a);
                x.f = h2f4[n * 6 + 2];
                a = FDOT2(x.h[0], w2u.h[0], a); a = FDOT2(x.h[1], w2u.h[1], a);
                a = FDOT2(x.h[2], w2u.h[2], a); a = FDOT2(x.h[3], w2u.h[3], a);
                x.f = h2f4[n * 6 + 3];
                a = FDOT2(x.h[0], w3.h[0], a); a = FDOT2(x.h[1], w3.h[1], a);
                a = FDOT2(x.h[2], w3.h[2], a); a = FDOT2(x.h[3], w3.h[3], a);
                x.f = h2f4[n * 6 + 4];
                a = FDOT2(x.h[0], w4.h[0], a); a = FDOT2(x.h[1], w4.h[1], a);
                a = FDOT2(x.h[2], w4.h[2], a); a = FDOT2(x.h[3], w4.h[3], a);
                x.f = h2f4[n * 6 + 5];
                a = FDOT2(x.h[0], w5.h[0], a); a = FDOT2(x.h[1], w5.h[1], a);
                a = FDOT2(x.h[2], w5.h[2], a); a = FDOT2(x.h[3], w5.h[3], a);
                float tv = tanh_fast(a + bq[kk]);
                sp[n] += tv * wq[kk];
            }
        }
        #pragma unroll
        for (int n = 0; n < 9; ++n) {
            sp[n] += __shfl_xor(sp[n], 1, 8);
            sp[n] += __shfl_xor(sp[n], 2, 8);
            sp[n] += __shfl_xor(sp[n], 4, 8);
        }

        // ---- H: node softmax (bp2 cancels) + weighted sum -> out ----
        float mx = sp[0];
        #pragma unroll
        for (int n = 1; n < 9; ++n) mx = fmaxf(mx, sp[n]);
        float wn9[9], sum = 0.f;
        #pragma unroll
        for (int n = 0; n < 9; ++n) { wn9[n] = __expf(sp[n] - mx); sum += wn9[n]; }
        float r = fast_rcp(sum);
        #pragma unroll
        for (int k = 0; k < 6; ++k) {
            float ov = 0.f;
            #pragma unroll
            for (int n = 0; n < 9; ++n) ov += wn9[n] * acc[n][k];
            out[(size_t)b * 48 + l8 + 8 * k] = ov * r;
        }
        WAVE_SYNC();
    }
}

extern "C" void kernel_launch(void* const* d_in, const int* in_sizes, int n_in,
                              void* d_out, int out_size, void* d_ws, size_t ws_size,
                              hipStream_t stream) {
    const float* obs = (const float*)d_in[0];
    const float* adj = (const float*)d_in[1];
    const float* W1  = (const float*)d_in[2];
    const float* a1  = (const float*)d_in[3];
    const float* W2  = (const float*)d_in[4];
    const float* a2  = (const float*)d_in[5];
    const float* Wp1 = (const float*)d_in[6];
    const float* bp1 = (const float*)d_in[7];
    const float* Wp2 = (const float*)d_in[8];
    float* out = (float*)d_out;
    h16* ws = (h16*)d_ws;

    const int B = in_sizes[0] / 9;

    prep_kernel<<<(48 * 96 + 576 + 255) / 256, 256, 0, stream>>>(W2, Wp1, ws);

    gnn_gat_kernel<<<4096, 128, 0, stream>>>(
        obs, adj, W1, a1, a2, bp1, Wp2, ws, out, B);
}